// Round 8
// baseline (777.538 us; speedup 1.0000x reference)
//
#include <hip/hip_runtime.h>
#include <hip/hip_fp16.h>

#define NN 8192
#define KDIM 256
#define FDIM 64

// ===== MEASUREMENT ROUND: output-invariant internal repeats push all three
// heavy kernels past the ~155us fill band into the rocprof top-5, with a
// same-run A/B of the two adjmask streaming patterns. =====
#define REP_ADJ 4
#define REP_P2  10

typedef __attribute__((ext_vector_type(8))) _Float16 f16x8;
typedef __attribute__((ext_vector_type(4))) float f32x4;

union H2U { __half2 h; unsigned u; };
union HU  { __half h; unsigned short u; };

__device__ __forceinline__ unsigned h2u(__half2 h) { H2U x; x.h = h; return x.u; }

__device__ __forceinline__ unsigned pkmul(unsigned a, unsigned b) {
    unsigned d; asm("v_pk_mul_f16 %0, %1, %2" : "=v"(d) : "v"(a), "v"(b)); return d;
}
__device__ __forceinline__ unsigned pkmax(unsigned a, unsigned b) {
    unsigned d; asm("v_pk_max_f16 %0, %1, %2" : "=v"(d) : "v"(a), "v"(b)); return d;
}

__device__ __forceinline__ float wred64(float v) {
    v += __shfl_xor(v, 1);
    v += __shfl_xor(v, 2);
    v += __shfl_xor(v, 4);
    v += __shfl_xor(v, 8);
    v += __shfl_xor(v, 16);
    v += __shfl_xor(v, 32);
    return v;
}

// Phase 1: Wh = h@W (f32 accum); emit Wh^T in MFMA-fragment order as fp16.
__global__ __launch_bounds__(256) void gat_phase1(
    const float* __restrict__ h, const float* __restrict__ W,
    const float* __restrict__ a, unsigned short* __restrict__ wfrag,
    float* __restrict__ fi, float* __restrict__ fj)
{
    __shared__ unsigned short wht_s[FDIM][20];
    const int tid = threadIdx.x;
    const int f  = tid & 63;
    const int rg = tid >> 6;
    const int i0 = blockIdx.x << 4;

    const float* __restrict__ h0 = h + (size_t)(i0 + rg * 4) * KDIM;
    const float* __restrict__ h1 = h0 + KDIM;
    const float* __restrict__ h2 = h0 + 2 * KDIM;
    const float* __restrict__ h3 = h0 + 3 * KDIM;

    float acc0 = 0.f, acc1 = 0.f, acc2 = 0.f, acc3 = 0.f;
    #pragma unroll 4
    for (int k4 = 0; k4 < KDIM / 4; ++k4) {
        const float4 r0 = *(const float4*)(h0 + k4 * 4);
        const float4 r1 = *(const float4*)(h1 + k4 * 4);
        const float4 r2 = *(const float4*)(h2 + k4 * 4);
        const float4 r3 = *(const float4*)(h3 + k4 * 4);
        const float w0 = W[(k4 * 4 + 0) * FDIM + f];
        const float w1 = W[(k4 * 4 + 1) * FDIM + f];
        const float w2 = W[(k4 * 4 + 2) * FDIM + f];
        const float w3 = W[(k4 * 4 + 3) * FDIM + f];
        acc0 += r0.x * w0 + r0.y * w1 + r0.z * w2 + r0.w * w3;
        acc1 += r1.x * w0 + r1.y * w1 + r1.z * w2 + r1.w * w3;
        acc2 += r2.x * w0 + r2.y * w1 + r2.z * w2 + r2.w * w3;
        acc3 += r3.x * w0 + r3.y * w1 + r3.z * w2 + r3.w * w3;
    }

    HU c0; c0.h = __float2half(acc0);
    HU c1; c1.h = __float2half(acc1);
    HU c2; c2.h = __float2half(acc2);
    HU c3; c3.h = __float2half(acc3);
    const int r0i = rg * 4;
    wht_s[f][r0i + 0] = c0.u;
    wht_s[f][r0i + 1] = c1.u;
    wht_s[f][r0i + 2] = c2.u;
    wht_s[f][r0i + 3] = c3.u;

    const float aL = a[f];
    const float aR = a[FDIM + f];
    float s;
    s = wred64(acc0 * aL); if (f == 0) fi[i0 + r0i + 0] = s;
    s = wred64(acc1 * aL); if (f == 0) fi[i0 + r0i + 1] = s;
    s = wred64(acc2 * aL); if (f == 0) fi[i0 + r0i + 2] = s;
    s = wred64(acc3 * aL); if (f == 0) fi[i0 + r0i + 3] = s;
    s = wred64(acc0 * aR); if (f == 0) fj[i0 + r0i + 0] = s;
    s = wred64(acc1 * aR); if (f == 0) fj[i0 + r0i + 1] = s;
    s = wred64(acc2 * aR); if (f == 0) fj[i0 + r0i + 2] = s;
    s = wred64(acc3 * aR); if (f == 0) fj[i0 + r0i + 3] = s;

    __syncthreads();
    if (tid < 128) {
        const int li2 = tid & 15;
        const int q2  = (tid >> 4) & 1;
        const int b   = tid >> 5;
        const int t   = i0 >> 5;
        const int hh  = (i0 >> 4) & 1;
        const int feat = b * 16 + li2;
        const ushort4 lo = *(const ushort4*)&wht_s[feat][q2 * 8];
        const ushort4 hi = *(const ushort4*)&wht_s[feat][q2 * 8 + 4];
        const int lg = (hh * 2 + q2) * 16 + li2;
        unsigned short* dst = wfrag + (size_t)t * 2048 + b * 512 + lg * 8;
        *(ushort4*)(dst)     = lo;
        *(ushort4*)(dst + 4) = hi;
    }
}

// Variant A: row-per-wave adj streaming (R6 style), byte-mask output.
// Word g of bm32 = bytes (0/0xFF) for ints 4g..4g+3 of adj. Idempotent.
__global__ __launch_bounds__(256) void gat_adjmask_row(
    const int4* __restrict__ adj4, unsigned* __restrict__ bm32)
{
    const int tid = threadIdx.x;
    const int l  = tid & 63;
    const int gw = (blockIdx.x << 2) | (tid >> 6);      // row
    const int4* __restrict__ row4 = adj4 + (size_t)gw * (NN / 4);
    unsigned* __restrict__ brow32 = bm32 + (size_t)gw * (NN / 4);

    for (int rep = 0; rep < REP_ADJ; ++rep) {
        #pragma unroll 1
        for (int base = 0; base < 32; base += 8) {
            int4 v[8];
            #pragma unroll
            for (int k = 0; k < 8; ++k)
                v[k] = row4[(base + k) * 64 + l];
            #pragma unroll
            for (int k = 0; k < 8; ++k) {
                const unsigned b = (v[k].x > 0 ? 0x000000FFu : 0u)
                                 | (v[k].y > 0 ? 0x0000FF00u : 0u)
                                 | (v[k].z > 0 ? 0x00FF0000u : 0u)
                                 | (v[k].w > 0 ? 0xFF000000u : 0u);
                brow32[(base + k) * 64 + l] = b;
            }
        }
        asm volatile("" ::: "memory");
    }
}

// Variant B: chip-address-order slice streaming (R7 style). Same output.
__global__ __launch_bounds__(256) void gat_adjmask_slice(
    const int4* __restrict__ adj4, unsigned* __restrict__ bm32)
{
    const int gtid = (blockIdx.x << 8) | threadIdx.x;
    const int TOT = 2048 * 256;
    for (int rep = 0; rep < REP_ADJ; ++rep) {
        #pragma unroll 1
        for (int s0 = 0; s0 < 32; s0 += 8) {
            int4 v[8];
            #pragma unroll
            for (int k = 0; k < 8; ++k)
                v[k] = adj4[(size_t)(s0 + k) * TOT + gtid];
            #pragma unroll
            for (int k = 0; k < 8; ++k) {
                const unsigned b = (v[k].x > 0 ? 0x000000FFu : 0u)
                                 | (v[k].y > 0 ? 0x0000FF00u : 0u)
                                 | (v[k].z > 0 ? 0x00FF0000u : 0u)
                                 | (v[k].w > 0 ? 0xFF000000u : 0u);
                bm32[(size_t)(s0 + k) * TOT + gtid] = b;
            }
        }
        asm volatile("" ::: "memory");
    }
}

// Phase 2b: fp16 packed math + byte-mask AND + 5th MFMA for z. (x REP_P2,
// acc and z scale together; v/zz invariant.)
__global__ __launch_bounds__(512, 4) void gat_phase2(
    const unsigned char* __restrict__ bm, const unsigned short* __restrict__ wfrag,
    const float* __restrict__ fi, const float* __restrict__ fjg,
    float* __restrict__ out)
{
    __shared__ unsigned Ebuf[NN];
    __shared__ float zred[128];

    const int tid = threadIdx.x;
    const int w  = tid >> 6;
    const int l  = tid & 63;
    const int li = l & 15;
    const int q  = l >> 4;
    const int qo = q * 8;
    const int i0 = blockIdx.x << 4;

    unsigned* E1p = Ebuf;
    unsigned* E2p = Ebuf + NN / 2;
    for (int t = tid; t < NN / 2; t += 512) {
        const float2 f2 = ((const float2*)fjg)[t];
        E1p[t] = h2u(__floats2half2_rn(__expf(f2.x), __expf(f2.y)));
        E2p[t] = h2u(__floats2half2_rn(__expf(0.2f * f2.x), __expf(0.2f * f2.y)));
    }
    __syncthreads();

    const float fiv = fi[i0 + li];
    const unsigned e1i2 = h2u(__floats2half2_rn(__expf(fiv), __expf(fiv)));
    const unsigned e2i2 = h2u(__floats2half2_rn(__expf(0.2f * fiv), __expf(0.2f * fiv)));

    const unsigned char*  __restrict__ brow = bm + (size_t)(i0 + li) * NN;
    const unsigned short* __restrict__ wf   = wfrag + l * 8;

    f32x4 acc0 = {0.f, 0.f, 0.f, 0.f};
    f32x4 acc1 = {0.f, 0.f, 0.f, 0.f};
    f32x4 acc2 = {0.f, 0.f, 0.f, 0.f};
    f32x4 acc3 = {0.f, 0.f, 0.f, 0.f};
    f32x4 accz = {0.f, 0.f, 0.f, 0.f};
    const f16x8 ones = { (_Float16)1.f, (_Float16)1.f, (_Float16)1.f, (_Float16)1.f,
                         (_Float16)1.f, (_Float16)1.f, (_Float16)1.f, (_Float16)1.f };

    for (int rep = 0; rep < REP_P2; ++rep) {
        #pragma unroll 4
        for (int tw = w; tw < NN / 32; tw += 8) {
            const int jg = tw * 32 + qo;
            const uint2 mw  = *(const uint2*)(brow + jg);
            const uint4 e1w = *(const uint4*)(E1p + (jg >> 1));
            const uint4 e2w = *(const uint4*)(E2p + (jg >> 1));
            const unsigned short* wt = wf + (size_t)tw * 2048;
            const f16x8 b0 = *(const f16x8*)(wt);
            const f16x8 b1 = *(const f16x8*)(wt + 512);
            const f16x8 b2 = *(const f16x8*)(wt + 1024);
            const f16x8 b3 = *(const f16x8*)(wt + 1536);

            const unsigned mm0 = __builtin_amdgcn_perm(0u, mw.x, 0x01010000u);
            const unsigned mm1 = __builtin_amdgcn_perm(0u, mw.x, 0x03030202u);
            const unsigned mm2 = __builtin_amdgcn_perm(0u, mw.y, 0x01010000u);
            const unsigned mm3 = __builtin_amdgcn_perm(0u, mw.y, 0x03030202u);

            union { unsigned u[4]; f16x8 v; } af;
            af.u[0] = pkmax(pkmul(e1i2, e1w.x), pkmul(e2i2, e2w.x)) & mm0;
            af.u[1] = pkmax(pkmul(e1i2, e1w.y), pkmul(e2i2, e2w.y)) & mm1;
            af.u[2] = pkmax(pkmul(e1i2, e1w.z), pkmul(e2i2, e2w.z)) & mm2;
            af.u[3] = pkmax(pkmul(e1i2, e1w.w), pkmul(e2i2, e2w.w)) & mm3;

            acc0 = __builtin_amdgcn_mfma_f32_16x16x32_f16(af.v, b0, acc0, 0, 0, 0);
            acc1 = __builtin_amdgcn_mfma_f32_16x16x32_f16(af.v, b1, acc1, 0, 0, 0);
            acc2 = __builtin_amdgcn_mfma_f32_16x16x32_f16(af.v, b2, acc2, 0, 0, 0);
            acc3 = __builtin_amdgcn_mfma_f32_16x16x32_f16(af.v, b3, acc3, 0, 0, 0);
            accz = __builtin_amdgcn_mfma_f32_16x16x32_f16(af.v, ones, accz, 0, 0, 0);
        }
        asm volatile("" ::: "memory");
    }

    __syncthreads();
    float* red = (float*)Ebuf;
    #pragma unroll
    for (int r = 0; r < 4; ++r) {
        red[(w * 16 + q * 4 + r) * 64 + 0 * 16 + li] = acc0[r];
        red[(w * 16 + q * 4 + r) * 64 + 1 * 16 + li] = acc1[r];
        red[(w * 16 + q * 4 + r) * 64 + 2 * 16 + li] = acc2[r];
        red[(w * 16 + q * 4 + r) * 64 + 3 * 16 + li] = acc3[r];
    }
    if (li == 0) {
        #pragma unroll
        for (int r = 0; r < 4; ++r)
            zred[w * 16 + q * 4 + r] = accz[r];
    }
    __syncthreads();

    const int f  = tid & 63;
    const int ig = tid >> 6;
    #pragma unroll
    for (int cc = 0; cc < 2; ++cc) {
        const int i = cc * 8 + ig;
        const float v = ((red[(0 * 16 + i) * 64 + f] + red[(1 * 16 + i) * 64 + f])
                       + (red[(2 * 16 + i) * 64 + f] + red[(3 * 16 + i) * 64 + f]))
                      + ((red[(4 * 16 + i) * 64 + f] + red[(5 * 16 + i) * 64 + f])
                       + (red[(6 * 16 + i) * 64 + f] + red[(7 * 16 + i) * 64 + f]));
        const float zz = ((zred[0 * 16 + i] + zred[1 * 16 + i]) + (zred[2 * 16 + i] + zred[3 * 16 + i]))
                       + ((zred[4 * 16 + i] + zred[5 * 16 + i]) + (zred[6 * 16 + i] + zred[7 * 16 + i]));
        out[(size_t)(i0 + i) * FDIM + f] = v / zz;
    }
}

extern "C" void kernel_launch(void* const* d_in, const int* in_sizes, int n_in,
                              void* d_out, int out_size, void* d_ws, size_t ws_size,
                              hipStream_t stream) {
    const float* h   = (const float*)d_in[0];
    const int*   adj = (const int*)d_in[1];
    const float* W   = (const float*)d_in[2];
    const float* a   = (const float*)d_in[3];
    float* out = (float*)d_out;

    unsigned short* wfrag = (unsigned short*)d_ws;                      // 1 MB @ 0
    float* fi = (float*)((char*)d_ws + (size_t)NN * FDIM * 2);          // 32 KB @ 1MB
    float* fj = fi + NN;                                                // 32 KB
    unsigned char* bm = (unsigned char*)d_ws + (2u << 20);              // 8 MB byte-mask @ 2MB

    gat_phase1<<<NN / 16, 256, 0, stream>>>(h, W, a, wfrag, fi, fj);
    gat_adjmask_row<<<NN / 4, 256, 0, stream>>>((const int4*)adj, (unsigned*)bm);
    gat_adjmask_slice<<<2048, 256, 0, stream>>>((const int4*)adj, (unsigned*)bm);
    gat_phase2<<<NN / 16, 512, 0, stream>>>(bm, wfrag, fi, fj, out);
}

// Round 10
// 145.943 us; speedup vs baseline: 5.3277x; 5.3277x over previous
//
#include <hip/hip_runtime.h>
#include <hip/hip_fp16.h>

#define NN 8192
#define KDIM 256
#define FDIM 64

typedef __attribute__((ext_vector_type(8))) _Float16 f16x8;
typedef __attribute__((ext_vector_type(4))) float f32x4;

union H2U { __half2 h; unsigned u; };
union HU  { __half h; unsigned short u; };

__device__ __forceinline__ unsigned h2u(__half2 h) { H2U x; x.h = h; return x.u; }

__device__ __forceinline__ unsigned pkmul(unsigned a, unsigned b) {
    unsigned d; asm("v_pk_mul_f16 %0, %1, %2" : "=v"(d) : "v"(a), "v"(b)); return d;
}
__device__ __forceinline__ unsigned pkmax(unsigned a, unsigned b) {
    unsigned d; asm("v_pk_max_f16 %0, %1, %2" : "=v"(d) : "v"(a), "v"(b)); return d;
}

__device__ __forceinline__ float wred64(float v) {
    v += __shfl_xor(v, 1);
    v += __shfl_xor(v, 2);
    v += __shfl_xor(v, 4);
    v += __shfl_xor(v, 8);
    v += __shfl_xor(v, 16);
    v += __shfl_xor(v, 32);
    return v;
}

// Phase 1: Wh = h@W (f32 accum); emit Wh^T in MFMA-fragment order as fp16.
// Also zeroes this block's slice of out/zbuf (accumulated by phase2 atomics).
__global__ __launch_bounds__(256) void gat_phase1(
    const float* __restrict__ h, const float* __restrict__ W,
    const float* __restrict__ a, unsigned short* __restrict__ wfrag,
    float* __restrict__ fi, float* __restrict__ fj,
    float* __restrict__ out, float* __restrict__ zbuf)
{
    __shared__ unsigned short wht_s[FDIM][20];
    const int tid = threadIdx.x;
    const int f  = tid & 63;
    const int rg = tid >> 6;
    const int i0 = blockIdx.x << 4;

    // zero the output slice this block owns (16 rows x 64 = 256 float4)
    const float4 zero4 = {0.f, 0.f, 0.f, 0.f};
    ((float4*)(out + (size_t)i0 * FDIM))[tid] = zero4;
    if (tid < 16) zbuf[i0 + tid] = 0.f;

    const float* __restrict__ h0 = h + (size_t)(i0 + rg * 4) * KDIM;
    const float* __restrict__ h1 = h0 + KDIM;
    const float* __restrict__ h2 = h0 + 2 * KDIM;
    const float* __restrict__ h3 = h0 + 3 * KDIM;

    float acc0 = 0.f, acc1 = 0.f, acc2 = 0.f, acc3 = 0.f;
    #pragma unroll 4
    for (int k4 = 0; k4 < KDIM / 4; ++k4) {
        const float4 r0 = *(const float4*)(h0 + k4 * 4);
        const float4 r1 = *(const float4*)(h1 + k4 * 4);
        const float4 r2 = *(const float4*)(h2 + k4 * 4);
        const float4 r3 = *(const float4*)(h3 + k4 * 4);
        const float w0 = W[(k4 * 4 + 0) * FDIM + f];
        const float w1 = W[(k4 * 4 + 1) * FDIM + f];
        const float w2 = W[(k4 * 4 + 2) * FDIM + f];
        const float w3 = W[(k4 * 4 + 3) * FDIM + f];
        acc0 += r0.x * w0 + r0.y * w1 + r0.z * w2 + r0.w * w3;
        acc1 += r1.x * w0 + r1.y * w1 + r1.z * w2 + r1.w * w3;
        acc2 += r2.x * w0 + r2.y * w1 + r2.z * w2 + r2.w * w3;
        acc3 += r3.x * w0 + r3.y * w1 + r3.z * w2 + r3.w * w3;
    }

    HU c0; c0.h = __float2half(acc0);
    HU c1; c1.h = __float2half(acc1);
    HU c2; c2.h = __float2half(acc2);
    HU c3; c3.h = __float2half(acc3);
    const int r0i = rg * 4;
    wht_s[f][r0i + 0] = c0.u;
    wht_s[f][r0i + 1] = c1.u;
    wht_s[f][r0i + 2] = c2.u;
    wht_s[f][r0i + 3] = c3.u;

    const float aL = a[f];
    const float aR = a[FDIM + f];
    float s;
    s = wred64(acc0 * aL); if (f == 0) fi[i0 + r0i + 0] = s;
    s = wred64(acc1 * aL); if (f == 0) fi[i0 + r0i + 1] = s;
    s = wred64(acc2 * aL); if (f == 0) fi[i0 + r0i + 2] = s;
    s = wred64(acc3 * aL); if (f == 0) fi[i0 + r0i + 3] = s;
    s = wred64(acc0 * aR); if (f == 0) fj[i0 + r0i + 0] = s;
    s = wred64(acc1 * aR); if (f == 0) fj[i0 + r0i + 1] = s;
    s = wred64(acc2 * aR); if (f == 0) fj[i0 + r0i + 2] = s;
    s = wred64(acc3 * aR); if (f == 0) fj[i0 + r0i + 3] = s;

    __syncthreads();
    if (tid < 128) {
        const int li2 = tid & 15;
        const int q2  = (tid >> 4) & 1;
        const int b   = tid >> 5;
        const int t   = i0 >> 5;
        const int hh  = (i0 >> 4) & 1;
        const int feat = b * 16 + li2;
        const ushort4 lo = *(const ushort4*)&wht_s[feat][q2 * 8];
        const ushort4 hi = *(const ushort4*)&wht_s[feat][q2 * 8 + 4];
        const int lg = (hh * 2 + q2) * 16 + li2;
        unsigned short* dst = wfrag + (size_t)t * 2048 + b * 512 + lg * 8;
        *(ushort4*)(dst)     = lo;
        *(ushort4*)(dst + 4) = hi;
    }
}

// Phase 2a: row-per-wave adj stream -> byte mask (R6/R8-measured variant).
__global__ __launch_bounds__(256) void gat_adjmask(
    const int4* __restrict__ adj4, unsigned* __restrict__ bm32)
{
    const int tid = threadIdx.x;
    const int l  = tid & 63;
    const int gw = (blockIdx.x << 2) | (tid >> 6);      // row
    const int4* __restrict__ row4 = adj4 + (size_t)gw * (NN / 4);
    unsigned* __restrict__ brow32 = bm32 + (size_t)gw * (NN / 4);

    #pragma unroll 1
    for (int base = 0; base < 32; base += 8) {
        int4 v[8];
        #pragma unroll
        for (int k = 0; k < 8; ++k)
            v[k] = row4[(base + k) * 64 + l];
        #pragma unroll
        for (int k = 0; k < 8; ++k) {
            const unsigned b = (v[k].x > 0 ? 0x000000FFu : 0u)
                             | (v[k].y > 0 ? 0x0000FF00u : 0u)
                             | (v[k].z > 0 ? 0x00FF0000u : 0u)
                             | (v[k].w > 0 ? 0xFF000000u : 0u);
            brow32[(base + k) * 64 + l] = b;
        }
    }
}

// Phase 2b: 2 column-half blocks per 16-row group (grid 1024 -> 4 blocks/CU),
// fp16 packed math, byte-mask AND, 5th MFMA for z; mask prefetched 1 iter ahead.
// Halves merge via deterministic f32 atomicAdd into zeroed out/zbuf.
__global__ __launch_bounds__(512, 8) void gat_phase2(
    const unsigned char* __restrict__ bm, const unsigned short* __restrict__ wfrag,
    const float* __restrict__ fi, const float* __restrict__ fjg,
    float* __restrict__ out, float* __restrict__ zbuf)
{
    __shared__ unsigned Ebuf[8192];   // loop: E1[0..2047] E2[2048..4095] (16 KB); epilogue: red (32 KB)
    __shared__ float zred[128];

    const int tid = threadIdx.x;
    const int w  = tid >> 6;   // 0..7
    const int l  = tid & 63;
    const int li = l & 15;
    const int q  = l >> 4;
    const int bid  = blockIdx.x;
    const int i0   = (bid >> 1) << 4;
    const int half = bid & 1;

    unsigned* E1p = Ebuf;
    unsigned* E2p = Ebuf + 2048;
    for (int t = tid; t < 2048; t += 512) {
        const float2 f2 = ((const float2*)fjg)[half * 2048 + t];
        E1p[t] = h2u(__floats2half2_rn(__expf(f2.x), __expf(f2.y)));
        E2p[t] = h2u(__floats2half2_rn(__expf(0.2f * f2.x), __expf(0.2f * f2.y)));
    }
    __syncthreads();

    const float fiv = fi[i0 + li];
    const unsigned e1i2 = h2u(__floats2half2_rn(__expf(fiv), __expf(fiv)));
    const unsigned e2i2 = h2u(__floats2half2_rn(__expf(0.2f * fiv), __expf(0.2f * fiv)));

    const uint2* __restrict__ brow2 =
        (const uint2*)(bm + (size_t)(i0 + li) * NN + half * (NN / 2));
    const unsigned short* __restrict__ wf =
        wfrag + (size_t)(half * 128) * 2048 + l * 8;

    f32x4 acc0 = {0.f, 0.f, 0.f, 0.f};
    f32x4 acc1 = {0.f, 0.f, 0.f, 0.f};
    f32x4 acc2 = {0.f, 0.f, 0.f, 0.f};
    f32x4 acc3 = {0.f, 0.f, 0.f, 0.f};
    f32x4 accz = {0.f, 0.f, 0.f, 0.f};
    const f16x8 ones = { (_Float16)1.f, (_Float16)1.f, (_Float16)1.f, (_Float16)1.f,
                         (_Float16)1.f, (_Float16)1.f, (_Float16)1.f, (_Float16)1.f };

    int tw = w;                         // local windows tw = w + 8s, s in [0,16)
    uint2 m_cur = brow2[tw * 4 + q];
    #pragma unroll 4
    for (int s = 0; s < 16; ++s) {
        uint2 m_nxt = m_cur;
        if (s < 15) m_nxt = brow2[(tw + 8) * 4 + q];   // prefetch next mask word
        const int ep = tw * 16 + q * 4;
        const uint4 e1w = *(const uint4*)(E1p + ep);
        const uint4 e2w = *(const uint4*)(E2p + ep);
        const unsigned short* wt = wf + (size_t)tw * 2048;
        const f16x8 b0 = *(const f16x8*)(wt);
        const f16x8 b1 = *(const f16x8*)(wt + 512);
        const f16x8 b2 = *(const f16x8*)(wt + 1024);
        const f16x8 b3 = *(const f16x8*)(wt + 1536);

        const unsigned mm0 = __builtin_amdgcn_perm(0u, m_cur.x, 0x01010000u);
        const unsigned mm1 = __builtin_amdgcn_perm(0u, m_cur.x, 0x03030202u);
        const unsigned mm2 = __builtin_amdgcn_perm(0u, m_cur.y, 0x01010000u);
        const unsigned mm3 = __builtin_amdgcn_perm(0u, m_cur.y, 0x03030202u);

        union { unsigned u[4]; f16x8 v; } af;
        af.u[0] = pkmax(pkmul(e1i2, e1w.x), pkmul(e2i2, e2w.x)) & mm0;
        af.u[1] = pkmax(pkmul(e1i2, e1w.y), pkmul(e2i2, e2w.y)) & mm1;
        af.u[2] = pkmax(pkmul(e1i2, e1w.z), pkmul(e2i2, e2w.z)) & mm2;
        af.u[3] = pkmax(pkmul(e1i2, e1w.w), pkmul(e2i2, e2w.w)) & mm3;

        acc0 = __builtin_amdgcn_mfma_f32_16x16x32_f16(af.v, b0, acc0, 0, 0, 0);
        acc1 = __builtin_amdgcn_mfma_f32_16x16x32_f16(af.v, b1, acc1, 0, 0, 0);
        acc2 = __builtin_amdgcn_mfma_f32_16x16x32_f16(af.v, b2, acc2, 0, 0, 0);
        acc3 = __builtin_amdgcn_mfma_f32_16x16x32_f16(af.v, b3, acc3, 0, 0, 0);
        accz = __builtin_amdgcn_mfma_f32_16x16x32_f16(af.v, ones, accz, 0, 0, 0);

        m_cur = m_nxt;
        tw += 8;
    }

    // epilogue: cross-wave reduce (red reuses Ebuf) + atomic merge of halves
    __syncthreads();
    float* red = (float*)Ebuf;
    #pragma unroll
    for (int r = 0; r < 4; ++r) {
        red[(w * 16 + q * 4 + r) * 64 + 0 * 16 + li] = acc0[r];
        red[(w * 16 + q * 4 + r) * 64 + 1 * 16 + li] = acc1[r];
        red[(w * 16 + q * 4 + r) * 64 + 2 * 16 + li] = acc2[r];
        red[(w * 16 + q * 4 + r) * 64 + 3 * 16 + li] = acc3[r];
    }
    if (li == 0) {
        #pragma unroll
        for (int r = 0; r < 4; ++r)
            zred[w * 16 + q * 4 + r] = accz[r];
    }
    __syncthreads();

    const int f  = tid & 63;
    const int ig = tid >> 6;   // 0..7
    #pragma unroll
    for (int cc = 0; cc < 2; ++cc) {
        const int i = cc * 8 + ig;
        const float v = ((red[(0 * 16 + i) * 64 + f] + red[(1 * 16 + i) * 64 + f])
                       + (red[(2 * 16 + i) * 64 + f] + red[(3 * 16 + i) * 64 + f]))
                      + ((red[(4 * 16 + i) * 64 + f] + red[(5 * 16 + i) * 64 + f])
                       + (red[(6 * 16 + i) * 64 + f] + red[(7 * 16 + i) * 64 + f]));
        atomicAdd(out + (size_t)(i0 + i) * FDIM + f, v);
        if (f == 0) {
            const float zz = ((zred[0 * 16 + i] + zred[1 * 16 + i]) + (zred[2 * 16 + i] + zred[3 * 16 + i]))
                           + ((zred[4 * 16 + i] + zred[5 * 16 + i]) + (zred[6 * 16 + i] + zred[7 * 16 + i]));
            atomicAdd(zbuf + i0 + i, zz);
        }
    }
}

// Final: out[i][f] /= z[i]   (131072 float4s)
__global__ __launch_bounds__(256) void gat_div(
    float* __restrict__ out, const float* __restrict__ zbuf)
{
    const int g = blockIdx.x * 256 + threadIdx.x;
    float4 v = ((const float4*)out)[g];
    const float z = zbuf[g >> 4];
    v.x /= z; v.y /= z; v.z /= z; v.w /= z;
    ((float4*)out)[g] = v;
}

extern "C" void kernel_launch(void* const* d_in, const int* in_sizes, int n_in,
                              void* d_out, int out_size, void* d_ws, size_t ws_size,
                              hipStream_t stream) {
    const float* h   = (const float*)d_in[0];
    const int*   adj = (const int*)d_in[1];
    const float* W   = (const float*)d_in[2];
    const float* a   = (const float*)d_in[3];
    float* out = (float*)d_out;

    // ws layout (bm is NN*NN bytes = 64 MB -- NOT 8 MB; R9's zbuf@10MB collided with it):
    unsigned short* wfrag = (unsigned short*)d_ws;                      // [0, 1MB)
    float* fi = (float*)((char*)d_ws + (size_t)NN * FDIM * 2);          // [1MB, +32KB)
    float* fj = fi + NN;                                                // [1MB+32KB, +32KB)
    float* zbuf = fj + NN;                                              // [1MB+64KB, +32KB) -- below bm
    unsigned char* bm = (unsigned char*)d_ws + (2u << 20);              // [2MB, 66MB) byte-mask

    gat_adjmask<<<NN / 4, 256, 0, stream>>>((const int4*)adj, (unsigned*)bm);
    gat_phase1<<<NN / 16, 256, 0, stream>>>(h, W, a, wfrag, fi, fj, out, zbuf);
    gat_phase2<<<NN / 8, 512, 0, stream>>>(bm, wfrag, fi, fj, out, zbuf);
    gat_div<<<NN * FDIM / 1024, 256, 0, stream>>>(out, zbuf);
}

// Round 12
// 93.550 us; speedup vs baseline: 8.3115x; 1.5601x over previous
//
#include <hip/hip_runtime.h>
#include <hip/hip_fp16.h>

#define NN 8192
#define KDIM 256
#define FDIM 64

typedef __attribute__((ext_vector_type(8))) _Float16 f16x8;
typedef __attribute__((ext_vector_type(4))) float f32x4;
typedef __attribute__((ext_vector_type(4))) int i32x4;

union H2U { __half2 h; unsigned u; };
union HU  { __half h; unsigned short u; };

__device__ __forceinline__ unsigned h2u(__half2 h) { H2U x; x.h = h; return x.u; }

__device__ __forceinline__ unsigned pkmul(unsigned a, unsigned b) {
    unsigned d; asm("v_pk_mul_f16 %0, %1, %2" : "=v"(d) : "v"(a), "v"(b)); return d;
}
__device__ __forceinline__ unsigned pkmax(unsigned a, unsigned b) {
    unsigned d; asm("v_pk_max_f16 %0, %1, %2" : "=v"(d) : "v"(a), "v"(b)); return d;
}

__device__ __forceinline__ float wred64(float v) {
    v += __shfl_xor(v, 1);
    v += __shfl_xor(v, 2);
    v += __shfl_xor(v, 4);
    v += __shfl_xor(v, 8);
    v += __shfl_xor(v, 16);
    v += __shfl_xor(v, 32);
    return v;
}

// Phase 1: Wh = h@W (f32 accum); emit Wh^T in MFMA-fragment order as fp16.
__global__ __launch_bounds__(256) void gat_phase1(
    const float* __restrict__ h, const float* __restrict__ W,
    const float* __restrict__ a, unsigned short* __restrict__ wfrag,
    float* __restrict__ fi, float* __restrict__ fj)
{
    __shared__ unsigned short wht_s[FDIM][20];
    const int tid = threadIdx.x;
    const int f  = tid & 63;
    const int rg = tid >> 6;
    const int i0 = blockIdx.x << 4;

    const float* __restrict__ h0 = h + (size_t)(i0 + rg * 4) * KDIM;
    const float* __restrict__ h1 = h0 + KDIM;
    const float* __restrict__ h2 = h0 + 2 * KDIM;
    const float* __restrict__ h3 = h0 + 3 * KDIM;

    float acc0 = 0.f, acc1 = 0.f, acc2 = 0.f, acc3 = 0.f;
    #pragma unroll 4
    for (int k4 = 0; k4 < KDIM / 4; ++k4) {
        const float4 r0 = *(const float4*)(h0 + k4 * 4);
        const float4 r1 = *(const float4*)(h1 + k4 * 4);
        const float4 r2 = *(const float4*)(h2 + k4 * 4);
        const float4 r3 = *(const float4*)(h3 + k4 * 4);
        const float w0 = W[(k4 * 4 + 0) * FDIM + f];
        const float w1 = W[(k4 * 4 + 1) * FDIM + f];
        const float w2 = W[(k4 * 4 + 2) * FDIM + f];
        const float w3 = W[(k4 * 4 + 3) * FDIM + f];
        acc0 += r0.x * w0 + r0.y * w1 + r0.z * w2 + r0.w * w3;
        acc1 += r1.x * w0 + r1.y * w1 + r1.z * w2 + r1.w * w3;
        acc2 += r2.x * w0 + r2.y * w1 + r2.z * w2 + r2.w * w3;
        acc3 += r3.x * w0 + r3.y * w1 + r3.z * w2 + r3.w * w3;
    }

    HU c0; c0.h = __float2half(acc0);
    HU c1; c1.h = __float2half(acc1);
    HU c2; c2.h = __float2half(acc2);
    HU c3; c3.h = __float2half(acc3);
    const int r0i = rg * 4;
    wht_s[f][r0i + 0] = c0.u;
    wht_s[f][r0i + 1] = c1.u;
    wht_s[f][r0i + 2] = c2.u;
    wht_s[f][r0i + 3] = c3.u;

    const float aL = a[f];
    const float aR = a[FDIM + f];
    float s;
    s = wred64(acc0 * aL); if (f == 0) fi[i0 + r0i + 0] = s;
    s = wred64(acc1 * aL); if (f == 0) fi[i0 + r0i + 1] = s;
    s = wred64(acc2 * aL); if (f == 0) fi[i0 + r0i + 2] = s;
    s = wred64(acc3 * aL); if (f == 0) fi[i0 + r0i + 3] = s;
    s = wred64(acc0 * aR); if (f == 0) fj[i0 + r0i + 0] = s;
    s = wred64(acc1 * aR); if (f == 0) fj[i0 + r0i + 1] = s;
    s = wred64(acc2 * aR); if (f == 0) fj[i0 + r0i + 2] = s;
    s = wred64(acc3 * aR); if (f == 0) fj[i0 + r0i + 3] = s;

    __syncthreads();
    if (tid < 128) {
        const int li2 = tid & 15;
        const int q2  = (tid >> 4) & 1;
        const int b   = tid >> 5;
        const int t   = i0 >> 5;
        const int hh  = (i0 >> 4) & 1;
        const int feat = b * 16 + li2;
        const ushort4 lo = *(const ushort4*)&wht_s[feat][q2 * 8];
        const ushort4 hi = *(const ushort4*)&wht_s[feat][q2 * 8 + 4];
        const int lg = (hh * 2 + q2) * 16 + li2;
        unsigned short* dst = wfrag + (size_t)t * 2048 + b * 512 + lg * 8;
        *(ushort4*)(dst)     = lo;
        *(ushort4*)(dst + 4) = hi;
    }
}

// Fused: block (i0, half) stages its 16 adj row-halves (contiguous NT int4
// reads) into an LDS bit-mask, then runs the fp16 MFMA loop. No global mask,
// no atomics: column-halves write disjoint partial buffers.
__global__ __launch_bounds__(512, 4) void gat_fused(
    const int* __restrict__ adj, const unsigned short* __restrict__ wfrag,
    const float* __restrict__ fi, const float* __restrict__ fjg,
    float* __restrict__ vpart, float* __restrict__ zpart)
{
    __shared__ unsigned mask_lds[16][129];   // bit-mask, padded -> conflict-free reads
    __shared__ unsigned Ebuf[4096];          // E1[0..2047] E2[2048..4095]; epilogue: red4 f32[4][16][64]
    __shared__ float zred[128];

    const int tid = threadIdx.x;
    const int w  = tid >> 6;   // 0..7
    const int l  = tid & 63;
    const int li = l & 15;
    const int q  = l >> 4;
    const int qo = q * 8;
    const int bid  = blockIdx.x;
    const int i0   = (bid >> 1) << 4;
    const int half = bid & 1;

    // ---- stage E tables for this half's fj ----
    unsigned* E1p = Ebuf;
    unsigned* E2p = Ebuf + 2048;
    for (int t = tid; t < 2048; t += 512) {
        const float2 f2 = ((const float2*)fjg)[half * 2048 + t];
        E1p[t] = h2u(__floats2half2_rn(__expf(f2.x), __expf(f2.y)));
        E2p[t] = h2u(__floats2half2_rn(__expf(0.2f * f2.x), __expf(0.2f * f2.y)));
    }

    // ---- stage adj -> LDS bit-mask (wave w: rows 2w, 2w+1; contiguous reads) ----
    const int wsel = (l & 7) * 4;
    #pragma unroll
    for (int j = 0; j < 2; ++j) {
        const int r = 2 * w + j;
        const i32x4* __restrict__ rowp =
            (const i32x4*)(adj + (size_t)(i0 + r) * NN + half * (NN / 2));
        #pragma unroll 1
        for (int g = 0; g < 16; g += 8) {
            i32x4 v[8];
            #pragma unroll
            for (int k = 0; k < 8; ++k)
                v[k] = __builtin_nontemporal_load(&rowp[(g + k) * 64 + l]);
            #pragma unroll
            for (int k = 0; k < 8; ++k) {
                unsigned nib = (unsigned)(v[k][0] > 0) | ((unsigned)(v[k][1] > 0) << 1)
                             | ((unsigned)(v[k][2] > 0) << 2) | ((unsigned)(v[k][3] > 0) << 3);
                unsigned part = nib << wsel;
                part |= __shfl_xor(part, 1);
                part |= __shfl_xor(part, 2);
                part |= __shfl_xor(part, 4);
                if ((l & 7) == 0) mask_lds[r][(g + k) * 8 + (l >> 3)] = part;
            }
        }
    }

    const float fiv = fi[i0 + li];
    const unsigned e1i2 = h2u(__floats2half2_rn(__expf(fiv), __expf(fiv)));
    const unsigned e2i2 = h2u(__floats2half2_rn(__expf(0.2f * fiv), __expf(0.2f * fiv)));
    const unsigned short* __restrict__ wf = wfrag + (size_t)(half * 128) * 2048 + l * 8;

    __syncthreads();

    f32x4 acc0 = {0.f, 0.f, 0.f, 0.f};
    f32x4 acc1 = {0.f, 0.f, 0.f, 0.f};
    f32x4 acc2 = {0.f, 0.f, 0.f, 0.f};
    f32x4 acc3 = {0.f, 0.f, 0.f, 0.f};
    f32x4 accz = {0.f, 0.f, 0.f, 0.f};
    const f16x8 ones = { (_Float16)1.f, (_Float16)1.f, (_Float16)1.f, (_Float16)1.f,
                         (_Float16)1.f, (_Float16)1.f, (_Float16)1.f, (_Float16)1.f };

    #pragma unroll 4
    for (int s = 0; s < 16; ++s) {
        const int tw = w + 8 * s;                    // local window 0..127
        const unsigned mword = mask_lds[li][tw];
        const unsigned mq8 = (mword >> qo) & 0xFFu;  // 8 mask bits for this lane
        const int ep = tw * 16 + q * 4;
        const uint4 e1w = *(const uint4*)(E1p + ep);
        const uint4 e2w = *(const uint4*)(E2p + ep);
        const unsigned short* wt = wf + (size_t)tw * 2048;
        const f16x8 b0 = *(const f16x8*)(wt);
        const f16x8 b1 = *(const f16x8*)(wt + 512);
        const f16x8 b2 = *(const f16x8*)(wt + 1024);
        const f16x8 b3 = *(const f16x8*)(wt + 1536);

        const unsigned mm0 = ((mq8 &   1u) ? 0x0000FFFFu : 0u) | ((mq8 &   2u) ? 0xFFFF0000u : 0u);
        const unsigned mm1 = ((mq8 &   4u) ? 0x0000FFFFu : 0u) | ((mq8 &   8u) ? 0xFFFF0000u : 0u);
        const unsigned mm2 = ((mq8 &  16u) ? 0x0000FFFFu : 0u) | ((mq8 &  32u) ? 0xFFFF0000u : 0u);
        const unsigned mm3 = ((mq8 &  64u) ? 0x0000FFFFu : 0u) | ((mq8 & 128u) ? 0xFFFF0000u : 0u);

        union { unsigned u[4]; f16x8 v; } af;
        af.u[0] = pkmax(pkmul(e1i2, e1w.x), pkmul(e2i2, e2w.x)) & mm0;
        af.u[1] = pkmax(pkmul(e1i2, e1w.y), pkmul(e2i2, e2w.y)) & mm1;
        af.u[2] = pkmax(pkmul(e1i2, e1w.z), pkmul(e2i2, e2w.z)) & mm2;
        af.u[3] = pkmax(pkmul(e1i2, e1w.w), pkmul(e2i2, e2w.w)) & mm3;

        acc0 = __builtin_amdgcn_mfma_f32_16x16x32_f16(af.v, b0, acc0, 0, 0, 0);
        acc1 = __builtin_amdgcn_mfma_f32_16x16x32_f16(af.v, b1, acc1, 0, 0, 0);
        acc2 = __builtin_amdgcn_mfma_f32_16x16x32_f16(af.v, b2, acc2, 0, 0, 0);
        acc3 = __builtin_amdgcn_mfma_f32_16x16x32_f16(af.v, b3, acc3, 0, 0, 0);
        accz = __builtin_amdgcn_mfma_f32_16x16x32_f16(af.v, ones, accz, 0, 0, 0);
    }

    // ---- epilogue: 2-round cross-wave reduce in Ebuf (16 KB), then partials ----
    __syncthreads();                      // Ebuf/mask reads done
    float* red4 = (float*)Ebuf;           // [4][16][64]
    if (li == 0) {
        #pragma unroll
        for (int r = 0; r < 4; ++r)
            zred[w * 16 + q * 4 + r] = accz[r];
    }
    if (w < 4) {
        #pragma unroll
        for (int r = 0; r < 4; ++r) {
            red4[(w * 16 + q * 4 + r) * 64 + 0 * 16 + li] = acc0[r];
            red4[(w * 16 + q * 4 + r) * 64 + 1 * 16 + li] = acc1[r];
            red4[(w * 16 + q * 4 + r) * 64 + 2 * 16 + li] = acc2[r];
            red4[(w * 16 + q * 4 + r) * 64 + 3 * 16 + li] = acc3[r];
        }
    }
    __syncthreads();
    if (w >= 4) {
        #pragma unroll
        for (int r = 0; r < 4; ++r) {
            red4[((w - 4) * 16 + q * 4 + r) * 64 + 0 * 16 + li] += acc0[r];
            red4[((w - 4) * 16 + q * 4 + r) * 64 + 1 * 16 + li] += acc1[r];
            red4[((w - 4) * 16 + q * 4 + r) * 64 + 2 * 16 + li] += acc2[r];
            red4[((w - 4) * 16 + q * 4 + r) * 64 + 3 * 16 + li] += acc3[r];
        }
    }
    __syncthreads();

    const int f  = tid & 63;
    const int ig = tid >> 6;   // 0..7
    #pragma unroll
    for (int cc = 0; cc < 2; ++cc) {
        const int i = cc * 8 + ig;
        const float v = (red4[(0 * 16 + i) * 64 + f] + red4[(1 * 16 + i) * 64 + f])
                      + (red4[(2 * 16 + i) * 64 + f] + red4[(3 * 16 + i) * 64 + f]);
        vpart[(size_t)(half * NN + i0 + i) * FDIM + f] = v;
        if (f == 0) {
            const float zz = ((zred[0 * 16 + i] + zred[1 * 16 + i]) + (zred[2 * 16 + i] + zred[3 * 16 + i]))
                           + ((zred[4 * 16 + i] + zred[5 * 16 + i]) + (zred[6 * 16 + i] + zred[7 * 16 + i]));
            zpart[half * NN + i0 + i] = zz;
        }
    }
}

// Merge halves: out = (v0+v1)/(z0+z1). 131072 float4.
__global__ __launch_bounds__(256) void gat_merge(
    const float* __restrict__ vpart, const float* __restrict__ zpart,
    float* __restrict__ out)
{
    const int g = blockIdx.x * 256 + threadIdx.x;
    const float4 a = ((const float4*)vpart)[g];
    const float4 b = ((const float4*)vpart)[g + NN * FDIM / 4];
    const int row = g >> 4;
    const float z = zpart[row] + zpart[row + NN];
    float4 o;
    o.x = (a.x + b.x) / z;
    o.y = (a.y + b.y) / z;
    o.z = (a.z + b.z) / z;
    o.w = (a.w + b.w) / z;
    ((float4*)out)[g] = o;
}

extern "C" void kernel_launch(void* const* d_in, const int* in_sizes, int n_in,
                              void* d_out, int out_size, void* d_ws, size_t ws_size,
                              hipStream_t stream) {
    const float* h   = (const float*)d_in[0];
    const int*   adj = (const int*)d_in[1];
    const float* W   = (const float*)d_in[2];
    const float* a   = (const float*)d_in[3];
    float* out = (float*)d_out;

    // ws layout (~6.1 MB total; ws proven >= 66 MB in R7/R8)
    unsigned short* wfrag = (unsigned short*)d_ws;                      // [0, 1MB)
    float* fi = (float*)((char*)d_ws + (size_t)NN * FDIM * 2);          // [1MB, +32KB)
    float* fj = fi + NN;                                                // +32KB
    float* vpart = (float*)((char*)d_ws + (2u << 20));                  // [2MB, +4MB) 2 halves
    float* zpart = (float*)((char*)d_ws + (6u << 20));                  // [6MB, +64KB)

    gat_phase1<<<NN / 16, 256, 0, stream>>>(h, W, a, wfrag, fi, fj);
    gat_fused<<<NN / 8, 512, 0, stream>>>(adj, wfrag, fi, fj, vpart, zpart);
    gat_merge<<<NN * FDIM / 1024, 256, 0, stream>>>(vpart, zpart, out);
}